// Round 1
// baseline (175.555 us; speedup 1.0000x reference)
//
#include <hip/hip_runtime.h>
#include <hip/hip_bf16.h>
#include <cstdint>
#include <cstddef>

#define TOKENS 8192
#define IN_F   1024
#define OUT_F  1024
#define KAUG   6144   // 1024 silu + 5*1024 jacobi (P0 folded into bias)

#define BM 128
#define BN 128
#define BK 64

typedef __attribute__((ext_vector_type(4))) float          f32x4;
typedef __attribute__((ext_vector_type(4))) float          float4v;
typedef __attribute__((ext_vector_type(8))) __bf16         bf16x8;
typedef __attribute__((ext_vector_type(8))) unsigned short ushort8;

// ---- f32 -> bf16 round-to-nearest-even (bit level, avoids class types) ----
__device__ __forceinline__ unsigned short f2bf(float f) {
    unsigned int u = __builtin_bit_cast(unsigned int, f);
    u += 0x7FFFu + ((u >> 16) & 1u);
    return (unsigned short)(u >> 16);
}

// ============================================================================
// Kernel 1: augmented activations  A_aug[b][j*1024+i], j=0: silu, j=1..5: P_j
// Each thread handles 8 consecutive i of one token b.
// ============================================================================
__global__ __launch_bounds__(256) void act_kernel(const float* __restrict__ x,
                                                  unsigned short* __restrict__ Aaug) {
    int gid = blockIdx.x * 256 + threadIdx.x;   // 0 .. TOKENS*IN_F/8 - 1
    int b   = gid >> 7;                         // IN_F/8 = 128 threads per token
    int i8  = (gid & 127) << 3;

    const float* xp = x + (size_t)b * IN_F + i8;
    float xs[8];
    *(float4v*)&xs[0] = *(const float4v*)xp;
    *(float4v*)&xs[4] = *(const float4v*)(xp + 4);

    // recurrence constants for A=B=1 (beta_n = 0):
    //   n=2: coefA=12t/24,  coefB=8/24
    //   n=3: coefA=64t/120, coefB=48/120
    //   n=4: coefA=180t/336,coefB=144/336
    //   n=5: coefA=384t/720,coefB=320/720
    unsigned short res[6][8];
    #pragma unroll
    for (int e = 0; e < 8; ++e) {
        float v  = xs[e];
        float s  = v / (1.f + __expf(-v));          // silu
        float t  = tanhf(v);
        float p1 = 2.f * t;                          // 0.5*(2*(A+1)*t + (A-B))
        float p2 = (12.f / 24.f) * t * p1 - (8.f / 24.f) * 1.f;
        float p3 = (64.f / 120.f) * t * p2 - (48.f / 120.f) * p1;
        float p4 = (180.f / 336.f) * t * p3 - (144.f / 336.f) * p2;
        float p5 = (384.f / 720.f) * t * p4 - (320.f / 720.f) * p3;
        res[0][e] = f2bf(s);
        res[1][e] = f2bf(p1);
        res[2][e] = f2bf(p2);
        res[3][e] = f2bf(p3);
        res[4][e] = f2bf(p4);
        res[5][e] = f2bf(p5);
    }
    unsigned short* dst = Aaug + (size_t)b * KAUG + i8;
    #pragma unroll
    for (int j = 0; j < 6; ++j)
        *(ushort8*)(dst + j * IN_F) = *(const ushort8*)&res[j][0];
}

// ============================================================================
// Kernel 2: weight repack to bf16 [OUT_F][KAUG] + bias fold of P0 coeffs.
// One block (256 threads) per output row o.
// ============================================================================
__global__ __launch_bounds__(256) void wt_kernel(const float* __restrict__ W,
                                                 const float* __restrict__ C,
                                                 const float* __restrict__ bias,
                                                 unsigned short* __restrict__ Baug,
                                                 float* __restrict__ bias_aug) {
    int o   = blockIdx.x;
    int tid = threadIdx.x;
    unsigned short* dst = Baug + (size_t)o * KAUG;
    float acc = 0.f;
    for (int i = tid; i < IN_F; i += 256) {
        float w = W[(size_t)o * IN_F + i];
        const float* c = C + ((size_t)o * IN_F + i) * 6;
        dst[i] = f2bf(w);
        #pragma unroll
        for (int j = 1; j < 6; ++j) dst[j * IN_F + i] = f2bf(c[j]);
        acc += c[0];                                  // P0 == 1 contribution
    }
    #pragma unroll
    for (int off = 32; off > 0; off >>= 1) acc += __shfl_down(acc, off, 64);
    __shared__ float red[4];
    int lane = tid & 63, wv = tid >> 6;
    if (lane == 0) red[wv] = acc;
    __syncthreads();
    if (tid == 0) bias_aug[o] = bias[o] + red[0] + red[1] + red[2] + red[3];
}

// ============================================================================
// Kernel 3: bf16 GEMM  out[M=8192][N=1024] = Aaug[M][K] * Baug[N][K]^T + bias
// m97-style: 128x128 tile, BK=64, 4 waves (2x2), global_load_lds width 16.
// ============================================================================
__global__ __launch_bounds__(256, 2) void gemm_kernel(
    const unsigned short* __restrict__ A,   // [TOKENS][KAUG] bf16
    const unsigned short* __restrict__ B,   // [OUT_F][KAUG]  bf16 (B^T layout)
    const float* __restrict__ bias_aug,     // [OUT_F]
    float* __restrict__ out)                // [TOKENS][OUT_F]
{
    __shared__ unsigned short As[BM][BK];   // 16 KB
    __shared__ unsigned short Bs[BN][BK];   // 16 KB

    const int tid  = threadIdx.x;
    const int lane = tid & 63;
    const int wave = tid >> 6;
    const int wr   = wave >> 1;             // wave row (M) in 2x2
    const int wc   = wave & 1;              // wave col (N)
    const int fr   = lane & 15;             // fragment row/col index
    const int fg   = lane >> 4;             // k-group (0..3)

    const int bn = blockIdx.x;              // N tile (8)
    const int bm = blockIdx.y;              // M tile (64)
    const size_t arow = (size_t)bm * BM;
    const size_t brow = (size_t)bn * BN;

    f32x4 acc[4][4] = {};

    for (int kb = 0; kb < KAUG; kb += BK) {
        // ---- stage A tile (128x64) and B tile (128x64) via global_load_lds x16
        #pragma unroll
        for (int s = 0; s < 4; ++s) {
            int off = s * 2048 + tid * 8;   // element offset in tile
            int r = off >> 6, c = off & 63;
            __builtin_amdgcn_global_load_lds(
                (const __attribute__((address_space(1))) void*)(A + (arow + r) * KAUG + kb + c),
                (__attribute__((address_space(3))) void*)(&As[0][0] + off), 16, 0, 0);
        }
        #pragma unroll
        for (int s = 0; s < 4; ++s) {
            int off = s * 2048 + tid * 8;
            int r = off >> 6, c = off & 63;
            __builtin_amdgcn_global_load_lds(
                (const __attribute__((address_space(1))) void*)(B + (brow + r) * KAUG + kb + c),
                (__attribute__((address_space(3))) void*)(&Bs[0][0] + off), 16, 0, 0);
        }
        __syncthreads();

        // ---- compute: 2 k-subtiles of 32, 16 MFMAs each
        #pragma unroll
        for (int ks = 0; ks < 2; ++ks) {
            bf16x8 af[4], bfr[4];
            #pragma unroll
            for (int mi = 0; mi < 4; ++mi)
                af[mi] = *(const bf16x8*)&As[wr * 64 + mi * 16 + fr][ks * 32 + fg * 8];
            #pragma unroll
            for (int ni = 0; ni < 4; ++ni)
                bfr[ni] = *(const bf16x8*)&Bs[wc * 64 + ni * 16 + fr][ks * 32 + fg * 8];
            #pragma unroll
            for (int mi = 0; mi < 4; ++mi)
                #pragma unroll
                for (int ni = 0; ni < 4; ++ni)
                    acc[mi][ni] = __builtin_amdgcn_mfma_f32_16x16x32_bf16(
                        af[mi], bfr[ni], acc[mi][ni], 0, 0, 0);
        }
        __syncthreads();
    }

    // ---- epilogue: D[row=(lane>>4)*4+reg][col=lane&15] + bias
    #pragma unroll
    for (int ni = 0; ni < 4; ++ni) {
        int col = bn * BN + wc * 64 + ni * 16 + fr;
        float bv = bias_aug[col];
        #pragma unroll
        for (int mi = 0; mi < 4; ++mi) {
            #pragma unroll
            for (int r = 0; r < 4; ++r) {
                int row = bm * BM + wr * 64 + mi * 16 + fg * 4 + r;
                out[(size_t)row * OUT_F + col] = acc[mi][ni][r] + bv;
            }
        }
    }
}

// ============================================================================
extern "C" void kernel_launch(void* const* d_in, const int* in_sizes, int n_in,
                              void* d_out, int out_size, void* d_ws, size_t ws_size,
                              hipStream_t stream) {
    const float* x    = (const float*)d_in[0];   // [8192][1024]
    const float* W    = (const float*)d_in[1];   // [1024][1024]
    const float* C    = (const float*)d_in[2];   // [1024][1024][6]
    const float* bias = (const float*)d_in[3];   // [1024]
    float* out = (float*)d_out;

    char* ws = (char*)d_ws;
    const size_t a_bytes = (size_t)TOKENS * KAUG * 2;     // 100.7 MB
    const size_t b_bytes = (size_t)OUT_F * KAUG * 2;      // 12.6 MB
    unsigned short* Aaug     = (unsigned short*)ws;
    unsigned short* Baug     = (unsigned short*)(ws + a_bytes);
    float*          bias_aug = (float*)(ws + a_bytes + b_bytes);

    hipLaunchKernelGGL(act_kernel, dim3(TOKENS * IN_F / 8 / 256), dim3(256), 0, stream,
                       x, Aaug);
    hipLaunchKernelGGL(wt_kernel, dim3(OUT_F), dim3(256), 0, stream,
                       W, C, bias, Baug, bias_aug);
    hipLaunchKernelGGL(gemm_kernel, dim3(OUT_F / BN, TOKENS / BM), dim3(256), 0, stream,
                       Aaug, Baug, bias_aug, out);
}

// Round 2
// 144.737 us; speedup vs baseline: 1.2129x; 1.2129x over previous
//
#include <hip/hip_runtime.h>
#include <hip/hip_bf16.h>
#include <cstdint>
#include <cstddef>

#define TOKENS 8192
#define IN_F   1024
#define OUT_F  1024
#define KAUG   6144          // 1024 silu + 5*1024 jacobi (P0 folded into bias)
#define KB_    12288         // KAUG * 2 bytes (row stride of Aaug/Baug)
#define KCHUNK 3072          // split-K = 2
#define NT     48            // KCHUNK / 64 tiles per chunk

typedef __attribute__((ext_vector_type(4))) float          f32x4;
typedef __attribute__((ext_vector_type(4))) float          float4v;
typedef __attribute__((ext_vector_type(8))) __bf16         bf16x8;
typedef __attribute__((ext_vector_type(8))) unsigned short ushort8;

__device__ __forceinline__ unsigned short f2bf(float f) {
    unsigned int u = __builtin_bit_cast(unsigned int, f);
    u += 0x7FFFu + ((u >> 16) & 1u);
    return (unsigned short)(u >> 16);
}

// ============================================================================
// Kernel 1: augmented activations  A_aug[b][j*1024+i], j=0: silu, j=1..5: P_j
// ============================================================================
__global__ __launch_bounds__(256) void act_kernel(const float* __restrict__ x,
                                                  unsigned short* __restrict__ Aaug) {
    int gid = blockIdx.x * 256 + threadIdx.x;
    int b   = gid >> 7;
    int i8  = (gid & 127) << 3;

    const float* xp = x + (size_t)b * IN_F + i8;
    float xs[8];
    *(float4v*)&xs[0] = *(const float4v*)xp;
    *(float4v*)&xs[4] = *(const float4v*)(xp + 4);

    unsigned short res[6][8];
    #pragma unroll
    for (int e = 0; e < 8; ++e) {
        float v  = xs[e];
        float s  = v / (1.f + __expf(-v));
        float t  = tanhf(v);
        float p1 = 2.f * t;
        float p2 = (12.f / 24.f) * t * p1 - (8.f / 24.f) * 1.f;
        float p3 = (64.f / 120.f) * t * p2 - (48.f / 120.f) * p1;
        float p4 = (180.f / 336.f) * t * p3 - (144.f / 336.f) * p2;
        float p5 = (384.f / 720.f) * t * p4 - (320.f / 720.f) * p3;
        res[0][e] = f2bf(s);
        res[1][e] = f2bf(p1);
        res[2][e] = f2bf(p2);
        res[3][e] = f2bf(p3);
        res[4][e] = f2bf(p4);
        res[5][e] = f2bf(p5);
    }
    unsigned short* dst = Aaug + (size_t)b * KAUG + i8;
    #pragma unroll
    for (int j = 0; j < 6; ++j)
        *(ushort8*)(dst + j * IN_F) = *(const ushort8*)&res[j][0];
}

// ============================================================================
// Kernel 2: weight repack to bf16 [OUT_F][KAUG] + bias fold of P0 coeffs.
// ============================================================================
__global__ __launch_bounds__(256) void wt_kernel(const float* __restrict__ W,
                                                 const float* __restrict__ C,
                                                 const float* __restrict__ bias,
                                                 unsigned short* __restrict__ Baug,
                                                 float* __restrict__ bias_aug) {
    int o   = blockIdx.x;
    int tid = threadIdx.x;
    unsigned short* dst = Baug + (size_t)o * KAUG;
    float acc = 0.f;
    for (int i = tid; i < IN_F; i += 256) {
        float w = W[(size_t)o * IN_F + i];
        const float* c = C + ((size_t)o * IN_F + i) * 6;
        dst[i] = f2bf(w);
        #pragma unroll
        for (int j = 1; j < 6; ++j) dst[j * IN_F + i] = f2bf(c[j]);
        acc += c[0];
    }
    #pragma unroll
    for (int off = 32; off > 0; off >>= 1) acc += __shfl_down(acc, off, 64);
    __shared__ float red[4];
    int lane = tid & 63, wv = tid >> 6;
    if (lane == 0) red[wv] = acc;
    __syncthreads();
    if (tid == 0) bias_aug[o] = bias[o] + red[0] + red[1] + red[2] + red[3];
}

// ============================================================================
// Kernel 3: 256x256x64 8-phase bf16 GEMM, split-K=2.
//   out(chunk0) / P1(chunk1) [8192][1024] f32 partials.
//   LDS 128KB: [buf:2][A 256x64 | B 256x64] bf16, XOR-swizzled columns
//   (linear gload_lds dest + inverse-swizzled global source, swizzled ds_read).
// ============================================================================
__global__ __launch_bounds__(512, 2) void gemm_kernel(
    const unsigned short* __restrict__ A,   // [TOKENS][KAUG] bf16
    const unsigned short* __restrict__ B,   // [OUT_F][KAUG]  bf16
    float* __restrict__ out,                // chunk 0 partial
    float* __restrict__ P1)                 // chunk 1 partial
{
    __shared__ unsigned short lds[65536];   // 128 KB
    char* ldsc = (char*)lds;

    const int tid  = threadIdx.x;
    const int lane = tid & 63;
    const int wave = tid >> 6;              // 0..7
    const int wr   = wave >> 2;             // 0..1  (M)
    const int wc   = wave & 3;              // 0..3  (N)
    const int fr   = lane & 15;
    const int fg   = lane >> 4;
    const int wrbase = wr * 128;
    const int wcbase = wc * 64;

    // block decode: XCD-friendly (the 4 bn sharing an A panel differ by 64 -> same XCD)
    const int bn    = blockIdx.x >> 6;        // 0..3
    const int bm    = (blockIdx.x >> 1) & 31; // 0..31
    const int chunk = blockIdx.x & 1;
    const int chunkoff = chunk * (KCHUNK * 2);

    // staging geometry: thread writes LDS bytes [j*8192 + tid*16, +16)
    // -> row r = j*64 + (tid>>3), dest colbyte cb' = (tid&7)*16
    // source colbyte = cb' ^ ((r&7)<<4); r&7 == (tid>>3)&7 (j*64 ≡ 0 mod 8)
    const int r0  = tid >> 3;
    const int scb = ((tid & 7) * 16) ^ ((r0 & 7) << 4);
    const char* gA = (const char*)A + (size_t)(bm * 256 + r0) * KB_ + chunkoff + scb;
    const char* gB = (const char*)B + (size_t)(bn * 256 + r0) * KB_ + chunkoff + scb;

    // ds_read swizzled column offsets (row&7 == fr&7 since 16|row-offsets)
    const int swz  = (fr & 7) << 4;
    const int kcs0 = (fg * 16) ^ swz;
    const int kcs1 = kcs0 ^ 64;

    f32x4 acc[8][4] = {};

#define STAGE(BUFSEL, MAT, KOFF) do {                                          \
    const char* gs_ = ((MAT) ? gB : gA) + (KOFF);                              \
    char* ls_ = ldsc + (BUFSEL) * 65536 + (MAT) * 32768 + tid * 16;            \
    _Pragma("unroll")                                                          \
    for (int j_ = 0; j_ < 4; ++j_)                                             \
        __builtin_amdgcn_global_load_lds(                                      \
            (const __attribute__((address_space(1))) void*)(gs_ + (size_t)j_ * 64 * KB_), \
            (__attribute__((address_space(3))) void*)(ls_ + j_ * 8192), 16, 0, 0); \
} while (0)

#define PHASE(QM, KS, DOSTAGE, MAT, KOFF, BOUND) do {                          \
    const int kcs_ = (KS) ? kcs1 : kcs0;                                       \
    bf16x8 a_[4], b_[4];                                                       \
    _Pragma("unroll")                                                          \
    for (int mi_ = 0; mi_ < 4; ++mi_)                                          \
        a_[mi_] = *(const bf16x8*)(ldsc + bufoff_ +                            \
                      (wrbase + (QM) * 64 + mi_ * 16 + fr) * 128 + kcs_);      \
    _Pragma("unroll")                                                          \
    for (int ni_ = 0; ni_ < 4; ++ni_)                                          \
        b_[ni_] = *(const bf16x8*)(ldsc + bufoff_ + 32768 +                    \
                      (wcbase + ni_ * 16 + fr) * 128 + kcs_);                  \
    if (DOSTAGE) STAGE(bufn_, MAT, KOFF);                                      \
    __builtin_amdgcn_s_barrier();                                              \
    __builtin_amdgcn_s_setprio(1);                                             \
    _Pragma("unroll")                                                          \
    for (int mi_ = 0; mi_ < 4; ++mi_)                                          \
        _Pragma("unroll")                                                      \
        for (int ni_ = 0; ni_ < 4; ++ni_)                                      \
            acc[(QM) * 4 + mi_][ni_] = __builtin_amdgcn_mfma_f32_16x16x32_bf16( \
                a_[mi_], b_[ni_], acc[(QM) * 4 + mi_][ni_], 0, 0, 0);          \
    __builtin_amdgcn_s_setprio(0);                                             \
    if (BOUND) asm volatile("s_waitcnt vmcnt(0)" ::: "memory");                \
    __builtin_amdgcn_s_barrier();                                              \
    if (BOUND) __builtin_amdgcn_sched_barrier(0);                              \
} while (0)

    // prologue: stage tile 0 -> buf 0, drain, barrier
    STAGE(0, 0, 0);
    STAGE(0, 1, 0);
    asm volatile("s_waitcnt vmcnt(0)" ::: "memory");
    __builtin_amdgcn_s_barrier();
    __builtin_amdgcn_sched_barrier(0);

    for (int t = 0; t < NT; ++t) {
        const int  b_      = t & 1;
        const int  bufoff_ = b_ * 65536;
        const int  bufn_   = b_ ^ 1;
        const int  koffn_  = (t + 1) * 128;
        const bool st_     = (t < NT - 1);
        PHASE(0, 0, st_,   0, koffn_, false);   // + stage A of t+1
        PHASE(0, 1, st_,   1, koffn_, false);   // + stage B of t+1
        PHASE(1, 0, false, 0, 0,      false);
        PHASE(1, 1, false, 0, 0,      st_);     // boundary: counted-drain + barrier
    }
#undef PHASE
#undef STAGE

    // epilogue: D row=(lane>>4)*4+reg, col=lane&15
    float* dst = chunk ? P1 : out;
    #pragma unroll
    for (int mi = 0; mi < 8; ++mi) {
        #pragma unroll
        for (int ni = 0; ni < 4; ++ni) {
            const int col = bn * 256 + wcbase + ni * 16 + fr;
            #pragma unroll
            for (int rr = 0; rr < 4; ++rr) {
                const int row = bm * 256 + wrbase + mi * 16 + fg * 4 + rr;
                dst[(size_t)row * OUT_F + col] = acc[mi][ni][rr];
            }
        }
    }
}

// ============================================================================
// Kernel 4: out = out(chunk0) + P1(chunk1) + bias
// ============================================================================
__global__ __launch_bounds__(256) void reduce_kernel(float* __restrict__ out,
                                                     const float* __restrict__ P1,
                                                     const float* __restrict__ bias) {
    const int total = TOKENS * OUT_F / 4;
    const float4v* p1 = (const float4v*)P1;
    const float4v* bi = (const float4v*)bias;
    float4v*       o  = (float4v*)out;
    for (int i = blockIdx.x * 256 + threadIdx.x; i < total; i += gridDim.x * 256)
        o[i] = o[i] + p1[i] + bi[i & 255];
}

// ============================================================================
extern "C" void kernel_launch(void* const* d_in, const int* in_sizes, int n_in,
                              void* d_out, int out_size, void* d_ws, size_t ws_size,
                              hipStream_t stream) {
    const float* x    = (const float*)d_in[0];
    const float* W    = (const float*)d_in[1];
    const float* C    = (const float*)d_in[2];
    const float* bias = (const float*)d_in[3];
    float* out = (float*)d_out;

    char* ws = (char*)d_ws;
    const size_t a_bytes = (size_t)TOKENS * KAUG * 2;   // 100.7 MB
    const size_t b_bytes = (size_t)OUT_F * KAUG * 2;    // 12.6 MB
    unsigned short* Aaug     = (unsigned short*)ws;
    unsigned short* Baug     = (unsigned short*)(ws + a_bytes);
    float*          bias_aug = (float*)(ws + a_bytes + b_bytes);
    float*          P1       = (float*)(ws + a_bytes + b_bytes + 4096);

    hipLaunchKernelGGL(act_kernel, dim3(TOKENS * IN_F / 8 / 256), dim3(256), 0, stream,
                       x, Aaug);
    hipLaunchKernelGGL(wt_kernel, dim3(OUT_F), dim3(256), 0, stream,
                       W, C, bias, Baug, bias_aug);
    hipLaunchKernelGGL(gemm_kernel, dim3(256), dim3(512), 0, stream,
                       Aaug, Baug, out, P1);
    hipLaunchKernelGGL(reduce_kernel, dim3(2048), dim3(256), 0, stream,
                       out, P1, bias_aug);
}